// Round 8
// baseline (244.822 us; speedup 1.0000x reference)
//
#include <hip/hip_runtime.h>
#include <cstdint>

#define NN 50000
#define NE 640000

typedef unsigned short ushort_t;

__device__ __forceinline__ ushort_t f2bf(float f) {
    unsigned int b = __float_as_uint(f);
    return (ushort_t)((b + 0x7FFF + ((b >> 16) & 1)) >> 16);   // RNE
}
__device__ __forceinline__ float bf2f(ushort_t u) {
    return __uint_as_float(((unsigned int)u) << 16);
}

// ---------------- CSR build ----------------
// 4 edges per thread (independent atomic chains -> 4x latency overlap)

__global__ void hist_kernel(const int* __restrict__ dst, int* __restrict__ cnt) {
    int tid = blockIdx.x * 256 + threadIdx.x;      // 160000 threads
#pragma unroll
    for (int k = 0; k < 4; ++k) {
        int e = tid + k * 160000;
        atomicAdd(&cnt[dst[e]], 1);
    }
}

// exclusive scan, 256-element blocks (Hillis-Steele in LDS)
__global__ void scan_block(const int* __restrict__ in, int* __restrict__ out,
                           int* __restrict__ partials, int n) {
    __shared__ int sm[256];
    int t = threadIdx.x;
    int gid = blockIdx.x * 256 + t;
    int v = (gid < n) ? in[gid] : 0;
    sm[t] = v;
    __syncthreads();
#pragma unroll
    for (int off = 1; off < 256; off <<= 1) {
        int add = (t >= off) ? sm[t - off] : 0;
        __syncthreads();
        sm[t] += add;
        __syncthreads();
    }
    if (gid < n) out[gid] = sm[t] - v;            // exclusive
    if (t == 255) partials[blockIdx.x] = sm[255];
}

__global__ void scan_partials(int* __restrict__ p, int nb) {
    __shared__ int sm[256];
    int t = threadIdx.x;
    int v = (t < nb) ? p[t] : 0;
    sm[t] = v;
    __syncthreads();
#pragma unroll
    for (int off = 1; off < 256; off <<= 1) {
        int add = (t >= off) ? sm[t - off] : 0;
        __syncthreads();
        sm[t] += add;
        __syncthreads();
    }
    if (t < nb) p[t] = sm[t] - v;                 // exclusive
}

// finalize offsets + init cursors + compute dinv (fused)
__global__ void finalize_offsets(int* __restrict__ offs, const int* __restrict__ partials,
                                 int* __restrict__ cursor, const int* __restrict__ cnt,
                                 float* __restrict__ dinv, int n) {
    int gid = blockIdx.x * 256 + threadIdx.x;
    if (gid < n) {
        int v = offs[gid] + partials[blockIdx.x];
        offs[gid] = v;
        cursor[gid] = v;
        dinv[gid] = rsqrtf((float)cnt[gid] + 1.0f);   // +1 for self-loop
    }
}

// CSR entry = src only (norm factored into GEMM epilogue + gather epilogue)
__global__ void csr_fill(const int* __restrict__ ei, int* __restrict__ cursor,
                         int* __restrict__ csr_src) {
    int tid = blockIdx.x * 256 + threadIdx.x;      // 160000 threads
#pragma unroll
    for (int k = 0; k < 4; ++k) {
        int e = tid + k * 160000;
        int s = ei[e], d = ei[NE + e];
        int pos = atomicAdd(&cursor[d], 1);
        csr_src[pos] = s;
    }
}

// ---------------- fp32 GEMM, K=128 (two 64-wide steps), 64x64 tile ----------------
// fp32 compute; output row-scaled by dinv[row], stored bf16.
// Round-5 lesson: register-prefetch A spills; keep LDS tiles (33.8 KB -> 4 blocks/CU).

__global__ __launch_bounds__(256) void gemm_k128_scaled(const float* __restrict__ A,
                                                        const float* __restrict__ B,
                                                        const float* __restrict__ dinv,
                                                        ushort_t* __restrict__ C,
                                                        int M, int N) {
    __shared__ float As[64][68];                  // +4 pad: 2-way bank alias only (free)
    __shared__ __align__(16) float Bs[64][64];
    const int t  = threadIdx.x;
    const int m0 = blockIdx.x * 64;
    const int n0 = blockIdx.y * 64;
    const int tx = t & 15, ty = t >> 4;

    float acc[4][4] = {};

    for (int ks = 0; ks < 2; ++ks) {
#pragma unroll
        for (int i = 0; i < 4; ++i) {
            int idx = i * 256 + t;
            int r = idx >> 4, c4 = idx & 15;
            int gm = m0 + r;
            float4 v = make_float4(0.f, 0.f, 0.f, 0.f);
            if (gm < M) v = *reinterpret_cast<const float4*>(&A[(size_t)gm * 128 + ks * 64 + c4 * 4]);
            As[r][c4 * 4 + 0] = v.x;
            As[r][c4 * 4 + 1] = v.y;
            As[r][c4 * 4 + 2] = v.z;
            As[r][c4 * 4 + 3] = v.w;
        }
#pragma unroll
        for (int i = 0; i < 4; ++i) {
            int idx = i * 256 + t;
            int k = idx >> 4, c4 = idx & 15;
            int gk = ks * 64 + k;
            int gn = n0 + c4 * 4;
            float4 v;
            v.x = (gn + 0 < N) ? B[(size_t)gk * N + gn + 0] : 0.f;
            v.y = (gn + 1 < N) ? B[(size_t)gk * N + gn + 1] : 0.f;
            v.z = (gn + 2 < N) ? B[(size_t)gk * N + gn + 2] : 0.f;
            v.w = (gn + 3 < N) ? B[(size_t)gk * N + gn + 3] : 0.f;
            *reinterpret_cast<float4*>(&Bs[k][c4 * 4]) = v;
        }
        __syncthreads();

#pragma unroll 8
        for (int k = 0; k < 64; ++k) {
            float a0 = As[ty * 4 + 0][k];
            float a1 = As[ty * 4 + 1][k];
            float a2 = As[ty * 4 + 2][k];
            float a3 = As[ty * 4 + 3][k];
            float4 b = *reinterpret_cast<const float4*>(&Bs[k][tx * 4]);
            acc[0][0] += a0 * b.x; acc[0][1] += a0 * b.y; acc[0][2] += a0 * b.z; acc[0][3] += a0 * b.w;
            acc[1][0] += a1 * b.x; acc[1][1] += a1 * b.y; acc[1][2] += a1 * b.z; acc[1][3] += a1 * b.w;
            acc[2][0] += a2 * b.x; acc[2][1] += a2 * b.y; acc[2][2] += a2 * b.z; acc[2][3] += a2 * b.w;
            acc[3][0] += a3 * b.x; acc[3][1] += a3 * b.y; acc[3][2] += a3 * b.z; acc[3][3] += a3 * b.w;
        }
        __syncthreads();
    }

#pragma unroll
    for (int i = 0; i < 4; ++i) {
        int gm = m0 + ty * 4 + i;
        if (gm >= M) continue;
        float s = dinv[gm];
        int gn = n0 + tx * 4;
        if (gn + 3 < N) {
            ushort4 o;
            o.x = f2bf(acc[i][0] * s); o.y = f2bf(acc[i][1] * s);
            o.z = f2bf(acc[i][2] * s); o.w = f2bf(acc[i][3] * s);
            *reinterpret_cast<ushort4*>(&C[(size_t)gm * N + gn]) = o;   // 8B aligned
        } else {
#pragma unroll
            for (int j = 0; j < 4; ++j)
                if (gn + j < N) C[(size_t)gm * N + gn + j] = f2bf(acc[i][j] * s);
        }
    }
}

// ---------------- gather layer 1 (128 ch bf16) + fused self-loop/bias/ReLU ----------------
// Hs = dinv[m]*H[m] already; result = relu(dinv[n]*(sum + Hs[n]) + b)
// one dst node per 32 lanes, lane owns 4 channels (ushort4 = 8B); edge loop unrolled x4

__global__ __launch_bounds__(256) void gather128(const int* __restrict__ offs,
                                                 const int* __restrict__ ends,
                                                 const int* __restrict__ csr_src,
                                                 const ushort_t* __restrict__ Hs,
                                                 const float* __restrict__ dinv,
                                                 const float* __restrict__ b1,
                                                 float* __restrict__ h) {
    const int c = (threadIdx.x & 31) * 4;
    const int n = (blockIdx.x * 256 + threadIdx.x) >> 5;    // grid exact: NN*32 threads
    const int beg = offs[n], end = ends[n];
    float4 acc = make_float4(0.f, 0.f, 0.f, 0.f);
    int j = beg;
    const int n4end = beg + ((end - beg) & ~3);
    for (; j < n4end; j += 4) {
        int s0 = csr_src[j + 0], s1 = csr_src[j + 1];
        int s2 = csr_src[j + 2], s3 = csr_src[j + 3];
        ushort4 v0 = *reinterpret_cast<const ushort4*>(Hs + (size_t)s0 * 128 + c);
        ushort4 v1 = *reinterpret_cast<const ushort4*>(Hs + (size_t)s1 * 128 + c);
        ushort4 v2 = *reinterpret_cast<const ushort4*>(Hs + (size_t)s2 * 128 + c);
        ushort4 v3 = *reinterpret_cast<const ushort4*>(Hs + (size_t)s3 * 128 + c);
        acc.x += bf2f(v0.x) + bf2f(v1.x) + bf2f(v2.x) + bf2f(v3.x);
        acc.y += bf2f(v0.y) + bf2f(v1.y) + bf2f(v2.y) + bf2f(v3.y);
        acc.z += bf2f(v0.z) + bf2f(v1.z) + bf2f(v2.z) + bf2f(v3.z);
        acc.w += bf2f(v0.w) + bf2f(v1.w) + bf2f(v2.w) + bf2f(v3.w);
    }
    for (; j < end; ++j) {
        int s = csr_src[j];
        ushort4 v = *reinterpret_cast<const ushort4*>(Hs + (size_t)s * 128 + c);
        acc.x += bf2f(v.x); acc.y += bf2f(v.y);
        acc.z += bf2f(v.z); acc.w += bf2f(v.w);
    }
    float di = dinv[n];
    ushort4 sv = *reinterpret_cast<const ushort4*>(Hs + (size_t)n * 128 + c);
    float4 bv = *reinterpret_cast<const float4*>(b1 + c);
    float4 r;
    r.x = fmaxf(fmaf(di, acc.x + bf2f(sv.x), bv.x), 0.f);
    r.y = fmaxf(fmaf(di, acc.y + bf2f(sv.y), bv.y), 0.f);
    r.z = fmaxf(fmaf(di, acc.z + bf2f(sv.z), bv.z), 0.f);
    r.w = fmaxf(fmaf(di, acc.w + bf2f(sv.w), bv.w), 0.f);
    *reinterpret_cast<float4*>(h + (size_t)n * 128 + c) = r;
}

// ---------------- gather layer 2 (40 ch bf16) + fused self-loop/bias ----------------
// one dst node per 10 lanes, lane owns 4 channels (ushort4); edge loop unrolled x4

__global__ __launch_bounds__(256) void gather40(const int* __restrict__ offs,
                                                const int* __restrict__ ends,
                                                const int* __restrict__ csr_src,
                                                const ushort_t* __restrict__ Hs,
                                                const float* __restrict__ dinv,
                                                const float* __restrict__ b2,
                                                float* __restrict__ out) {
    int idx = blockIdx.x * 256 + threadIdx.x;
    if (idx >= NN * 10) return;
    const int n = idx / 10;
    const int c = (idx - n * 10) * 4;
    const int beg = offs[n], end = ends[n];
    float4 acc = make_float4(0.f, 0.f, 0.f, 0.f);
    int j = beg;
    const int n4end = beg + ((end - beg) & ~3);
    for (; j < n4end; j += 4) {
        int s0 = csr_src[j + 0], s1 = csr_src[j + 1];
        int s2 = csr_src[j + 2], s3 = csr_src[j + 3];
        ushort4 v0 = *reinterpret_cast<const ushort4*>(Hs + (size_t)s0 * 40 + c);
        ushort4 v1 = *reinterpret_cast<const ushort4*>(Hs + (size_t)s1 * 40 + c);
        ushort4 v2 = *reinterpret_cast<const ushort4*>(Hs + (size_t)s2 * 40 + c);
        ushort4 v3 = *reinterpret_cast<const ushort4*>(Hs + (size_t)s3 * 40 + c);
        acc.x += bf2f(v0.x) + bf2f(v1.x) + bf2f(v2.x) + bf2f(v3.x);
        acc.y += bf2f(v0.y) + bf2f(v1.y) + bf2f(v2.y) + bf2f(v3.y);
        acc.z += bf2f(v0.z) + bf2f(v1.z) + bf2f(v2.z) + bf2f(v3.z);
        acc.w += bf2f(v0.w) + bf2f(v1.w) + bf2f(v2.w) + bf2f(v3.w);
    }
    for (; j < end; ++j) {
        int s = csr_src[j];
        ushort4 v = *reinterpret_cast<const ushort4*>(Hs + (size_t)s * 40 + c);
        acc.x += bf2f(v.x); acc.y += bf2f(v.y);
        acc.z += bf2f(v.z); acc.w += bf2f(v.w);
    }
    float di = dinv[n];
    ushort4 sv = *reinterpret_cast<const ushort4*>(Hs + (size_t)n * 40 + c);
    float4 bv = *reinterpret_cast<const float4*>(b2 + c);
    float4 r;
    r.x = fmaf(di, acc.x + bf2f(sv.x), bv.x);
    r.y = fmaf(di, acc.y + bf2f(sv.y), bv.y);
    r.z = fmaf(di, acc.z + bf2f(sv.z), bv.z);
    r.w = fmaf(di, acc.w + bf2f(sv.w), bv.w);
    *reinterpret_cast<float4*>(out + (size_t)n * 40 + c) = r;
}

// ---------------- launch ----------------

extern "C" void kernel_launch(void* const* d_in, const int* in_sizes, int n_in,
                              void* d_out, int out_size, void* d_ws, size_t ws_size,
                              hipStream_t stream) {
    const float* x  = (const float*)d_in[0];
    const int*   ei = (const int*)d_in[1];     // [2, NE]: row0 = src, row1 = dst
    const float* W1 = (const float*)d_in[2];
    const float* b1 = (const float*)d_in[3];
    const float* W2 = (const float*)d_in[4];
    const float* b2 = (const float*)d_in[5];
    float* out = (float*)d_out;

    // workspace layout (4B elements)
    int*      deg_i    = (int*)d_ws;                   // [50048]
    float*    dinv     = (float*)d_ws + 50048;         // [50048]
    int*      offs     = (int*)d_ws + 100096;          // [50048]
    int*      cursor   = (int*)d_ws + 150144;          // [50048] -> ends after csr_fill
    int*      partials = (int*)d_ws + 200192;          // [512]
    int*      csr_src  = (int*)d_ws + 200704;          // [640000] src only
    ushort_t* H1b      = (ushort_t*)((int*)d_ws + 840704); // NN*128 bf16 = 3.2M ints
    float*    h        = (float*)d_ws + 4040704;       // [6400000]
    ushort_t* H2b      = H1b;                          // alias: H1 dead after gather128

    const int NB = (NN + 255) / 256;                   // 196 scan blocks

    // CSR build
    hipMemsetAsync(deg_i, 0, NN * sizeof(int), stream);
    hist_kernel<<<625, 256, 0, stream>>>(ei + NE, deg_i);
    scan_block<<<NB, 256, 0, stream>>>(deg_i, offs, partials, NN);
    scan_partials<<<1, 256, 0, stream>>>(partials, NB);
    finalize_offsets<<<NB, 256, 0, stream>>>(offs, partials, cursor, deg_i, dinv, NN);
    csr_fill<<<625, 256, 0, stream>>>(ei, cursor, csr_src);

    // layer 1: H1b = dinv[m] * (x @ W1), bf16
    gemm_k128_scaled<<<dim3((NN + 63) / 64, 2), 256, 0, stream>>>(x, W1, dinv, H1b, NN, 128);
    gather128<<<NN * 32 / 256, 256, 0, stream>>>(offs, cursor, csr_src, H1b, dinv, b1, h);

    // layer 2: H2b = dinv[m] * (h @ W2), bf16
    gemm_k128_scaled<<<dim3((NN + 63) / 64, 1), 256, 0, stream>>>(h, W2, dinv, H2b, NN, 40);
    gather40<<<(NN * 10 + 255) / 256, 256, 0, stream>>>(offs, cursor, csr_src, H2b, dinv, b2, out);
}

// Round 12
// 230.368 us; speedup vs baseline: 1.0627x; 1.0627x over previous
//
#include <hip/hip_runtime.h>
#include <cstdint>

#define NN 50000
#define NE 640000
#define NFILL 625                                  // csr_fill blocks in fused kernel
#define MB1 782                                    // (NN+63)/64 GEMM row-blocks

typedef unsigned short ushort_t;

__device__ __forceinline__ ushort_t f2bf(float f) {
    unsigned int b = __float_as_uint(f);
    return (ushort_t)((b + 0x7FFF + ((b >> 16) & 1)) >> 16);   // RNE
}
__device__ __forceinline__ float bf2f(ushort_t u) {
    return __uint_as_float(((unsigned int)u) << 16);
}

// ---------------- CSR build ----------------

__global__ void hist_kernel(const int* __restrict__ dst, int* __restrict__ cnt) {
    int tid = blockIdx.x * 256 + threadIdx.x;      // 160000 threads
#pragma unroll
    for (int k = 0; k < 4; ++k) {
        int e = tid + k * 160000;
        atomicAdd(&cnt[dst[e]], 1);
    }
}

// exclusive scan, 256-element blocks (Hillis-Steele in LDS)
__global__ void scan_block(const int* __restrict__ in, int* __restrict__ out,
                           int* __restrict__ partials, int n) {
    __shared__ int sm[256];
    int t = threadIdx.x;
    int gid = blockIdx.x * 256 + t;
    int v = (gid < n) ? in[gid] : 0;
    sm[t] = v;
    __syncthreads();
#pragma unroll
    for (int off = 1; off < 256; off <<= 1) {
        int add = (t >= off) ? sm[t - off] : 0;
        __syncthreads();
        sm[t] += add;
        __syncthreads();
    }
    if (gid < n) out[gid] = sm[t] - v;            // exclusive
    if (t == 255) partials[blockIdx.x] = sm[255];
}

__global__ void scan_partials(int* __restrict__ p, int nb) {
    __shared__ int sm[256];
    int t = threadIdx.x;
    int v = (t < nb) ? p[t] : 0;
    sm[t] = v;
    __syncthreads();
#pragma unroll
    for (int off = 1; off < 256; off <<= 1) {
        int add = (t >= off) ? sm[t - off] : 0;
        __syncthreads();
        sm[t] += add;
        __syncthreads();
    }
    if (t < nb) p[t] = sm[t] - v;                 // exclusive
}

// finalize offsets + init cursors + compute dinv (fused)
__global__ void finalize_offsets(int* __restrict__ offs, const int* __restrict__ partials,
                                 int* __restrict__ cursor, const int* __restrict__ cnt,
                                 float* __restrict__ dinv, int n) {
    int gid = blockIdx.x * 256 + threadIdx.x;
    if (gid < n) {
        int v = offs[gid] + partials[blockIdx.x];
        offs[gid] = v;
        cursor[gid] = v;
        dinv[gid] = rsqrtf((float)cnt[gid] + 1.0f);   // +1 for self-loop
    }
}

// ---------------- fused: csr_fill (blocks 0..NFILL-1)  |  scaled GEMM1 (rest) ------
// csr_fill is TCC/latency-bound (VALU 0.25%); GEMM is VALU-bound -> overlap.
// csr entries are ushort (node id < 65536): halves scattered-store churn.
// GEMM: fp32, K=128 as two 64-wide steps, 64x64 tile, LDS 33.8 KB -> 4 blocks/CU.
// (Round-5 lesson: register-prefetch A spills; keep LDS tiles.)

__global__ __launch_bounds__(256) void fused_fill_gemm(const int* __restrict__ ei,
                                                       int* __restrict__ cursor,
                                                       ushort_t* __restrict__ csr_src,
                                                       const float* __restrict__ A,
                                                       const float* __restrict__ B,
                                                       const float* __restrict__ dinv,
                                                       ushort_t* __restrict__ C,
                                                       int M, int N) {
    __shared__ float As[64][68];                  // +4 pad: 2-way bank alias only (free)
    __shared__ __align__(16) float Bs[64][64];

    if (blockIdx.x < NFILL) {
        // ---- csr_fill part: 4 independent edges per thread ----
        int tid = blockIdx.x * 256 + threadIdx.x;  // 160000 threads
#pragma unroll
        for (int k = 0; k < 4; ++k) {
            int e = tid + k * 160000;
            int s = ei[e], d = ei[NE + e];
            int pos = atomicAdd(&cursor[d], 1);
            csr_src[pos] = (ushort_t)s;
        }
        return;
    }

    // ---- GEMM part ----
    const int b  = blockIdx.x - NFILL;
    const int t  = threadIdx.x;
    const int m0 = (b % MB1) * 64;
    const int n0 = (b / MB1) * 64;
    const int tx = t & 15, ty = t >> 4;

    float acc[4][4] = {};

    for (int ks = 0; ks < 2; ++ks) {
#pragma unroll
        for (int i = 0; i < 4; ++i) {
            int idx = i * 256 + t;
            int r = idx >> 4, c4 = idx & 15;
            int gm = m0 + r;
            float4 v = make_float4(0.f, 0.f, 0.f, 0.f);
            if (gm < M) v = *reinterpret_cast<const float4*>(&A[(size_t)gm * 128 + ks * 64 + c4 * 4]);
            As[r][c4 * 4 + 0] = v.x;
            As[r][c4 * 4 + 1] = v.y;
            As[r][c4 * 4 + 2] = v.z;
            As[r][c4 * 4 + 3] = v.w;
        }
#pragma unroll
        for (int i = 0; i < 4; ++i) {
            int idx = i * 256 + t;
            int k = idx >> 4, c4 = idx & 15;
            int gk = ks * 64 + k;
            int gn = n0 + c4 * 4;
            float4 v;
            v.x = (gn + 0 < N) ? B[(size_t)gk * N + gn + 0] : 0.f;
            v.y = (gn + 1 < N) ? B[(size_t)gk * N + gn + 1] : 0.f;
            v.z = (gn + 2 < N) ? B[(size_t)gk * N + gn + 2] : 0.f;
            v.w = (gn + 3 < N) ? B[(size_t)gk * N + gn + 3] : 0.f;
            *reinterpret_cast<float4*>(&Bs[k][c4 * 4]) = v;
        }
        __syncthreads();

#pragma unroll 8
        for (int k = 0; k < 64; ++k) {
            float a0 = As[ty * 4 + 0][k];
            float a1 = As[ty * 4 + 1][k];
            float a2 = As[ty * 4 + 2][k];
            float a3 = As[ty * 4 + 3][k];
            float4 bb = *reinterpret_cast<const float4*>(&Bs[k][tx * 4]);
            acc[0][0] += a0 * bb.x; acc[0][1] += a0 * bb.y; acc[0][2] += a0 * bb.z; acc[0][3] += a0 * bb.w;
            acc[1][0] += a1 * bb.x; acc[1][1] += a1 * bb.y; acc[1][2] += a1 * bb.z; acc[1][3] += a1 * bb.w;
            acc[2][0] += a2 * bb.x; acc[2][1] += a2 * bb.y; acc[2][2] += a2 * bb.z; acc[2][3] += a2 * bb.w;
            acc[3][0] += a3 * bb.x; acc[3][1] += a3 * bb.y; acc[3][2] += a3 * bb.z; acc[3][3] += a3 * bb.w;
        }
        __syncthreads();
    }

#pragma unroll
    for (int i = 0; i < 4; ++i) {
        int gm = m0 + ty * 4 + i;
        if (gm >= M) continue;
        float s = dinv[gm];
        int gn = n0 + tx * 4;
        if (gn + 3 < N) {
            ushort4 o;
            o.x = f2bf(acc[i][0] * s); o.y = f2bf(acc[i][1] * s);
            o.z = f2bf(acc[i][2] * s); o.w = f2bf(acc[i][3] * s);
            *reinterpret_cast<ushort4*>(&C[(size_t)gm * N + gn]) = o;   // 8B aligned
        } else {
#pragma unroll
            for (int j = 0; j < 4; ++j)
                if (gn + j < N) C[(size_t)gm * N + gn + j] = f2bf(acc[i][j] * s);
        }
    }
}

// ---------------- plain scaled GEMM (layer 2, N=40) ----------------

__global__ __launch_bounds__(256) void gemm_k128_scaled(const float* __restrict__ A,
                                                        const float* __restrict__ B,
                                                        const float* __restrict__ dinv,
                                                        ushort_t* __restrict__ C,
                                                        int M, int N) {
    __shared__ float As[64][68];
    __shared__ __align__(16) float Bs[64][64];
    const int t  = threadIdx.x;
    const int m0 = blockIdx.x * 64;
    const int n0 = blockIdx.y * 64;
    const int tx = t & 15, ty = t >> 4;

    float acc[4][4] = {};

    for (int ks = 0; ks < 2; ++ks) {
#pragma unroll
        for (int i = 0; i < 4; ++i) {
            int idx = i * 256 + t;
            int r = idx >> 4, c4 = idx & 15;
            int gm = m0 + r;
            float4 v = make_float4(0.f, 0.f, 0.f, 0.f);
            if (gm < M) v = *reinterpret_cast<const float4*>(&A[(size_t)gm * 128 + ks * 64 + c4 * 4]);
            As[r][c4 * 4 + 0] = v.x;
            As[r][c4 * 4 + 1] = v.y;
            As[r][c4 * 4 + 2] = v.z;
            As[r][c4 * 4 + 3] = v.w;
        }
#pragma unroll
        for (int i = 0; i < 4; ++i) {
            int idx = i * 256 + t;
            int k = idx >> 4, c4 = idx & 15;
            int gk = ks * 64 + k;
            int gn = n0 + c4 * 4;
            float4 v;
            v.x = (gn + 0 < N) ? B[(size_t)gk * N + gn + 0] : 0.f;
            v.y = (gn + 1 < N) ? B[(size_t)gk * N + gn + 1] : 0.f;
            v.z = (gn + 2 < N) ? B[(size_t)gk * N + gn + 2] : 0.f;
            v.w = (gn + 3 < N) ? B[(size_t)gk * N + gn + 3] : 0.f;
            *reinterpret_cast<float4*>(&Bs[k][c4 * 4]) = v;
        }
        __syncthreads();

#pragma unroll 8
        for (int k = 0; k < 64; ++k) {
            float a0 = As[ty * 4 + 0][k];
            float a1 = As[ty * 4 + 1][k];
            float a2 = As[ty * 4 + 2][k];
            float a3 = As[ty * 4 + 3][k];
            float4 bb = *reinterpret_cast<const float4*>(&Bs[k][tx * 4]);
            acc[0][0] += a0 * bb.x; acc[0][1] += a0 * bb.y; acc[0][2] += a0 * bb.z; acc[0][3] += a0 * bb.w;
            acc[1][0] += a1 * bb.x; acc[1][1] += a1 * bb.y; acc[1][2] += a1 * bb.z; acc[1][3] += a1 * bb.w;
            acc[2][0] += a2 * bb.x; acc[2][1] += a2 * bb.y; acc[2][2] += a2 * bb.z; acc[2][3] += a2 * bb.w;
            acc[3][0] += a3 * bb.x; acc[3][1] += a3 * bb.y; acc[3][2] += a3 * bb.z; acc[3][3] += a3 * bb.w;
        }
        __syncthreads();
    }

#pragma unroll
    for (int i = 0; i < 4; ++i) {
        int gm = m0 + ty * 4 + i;
        if (gm >= M) continue;
        float s = dinv[gm];
        int gn = n0 + tx * 4;
        if (gn + 3 < N) {
            ushort4 o;
            o.x = f2bf(acc[i][0] * s); o.y = f2bf(acc[i][1] * s);
            o.z = f2bf(acc[i][2] * s); o.w = f2bf(acc[i][3] * s);
            *reinterpret_cast<ushort4*>(&C[(size_t)gm * N + gn]) = o;
        } else {
#pragma unroll
            for (int j = 0; j < 4; ++j)
                if (gn + j < N) C[(size_t)gm * N + gn + j] = f2bf(acc[i][j] * s);
        }
    }
}

// ---------------- gather layer 1 (128 ch bf16) + fused self-loop/bias/ReLU ----------------
// Hs = dinv[m]*H[m]; result = relu(dinv[n]*(sum + Hs[n]) + b)
// one dst node per 32 lanes, lane owns 4 channels (ushort4 = 8B); edge loop unrolled x4

__global__ __launch_bounds__(256) void gather128(const int* __restrict__ offs,
                                                 const int* __restrict__ ends,
                                                 const ushort_t* __restrict__ csr_src,
                                                 const ushort_t* __restrict__ Hs,
                                                 const float* __restrict__ dinv,
                                                 const float* __restrict__ b1,
                                                 float* __restrict__ h) {
    const int c = (threadIdx.x & 31) * 4;
    const int n = (blockIdx.x * 256 + threadIdx.x) >> 5;    // grid exact: NN*32 threads
    const int beg = offs[n], end = ends[n];
    float4 acc = make_float4(0.f, 0.f, 0.f, 0.f);
    int j = beg;
    const int n4end = beg + ((end - beg) & ~3);
    for (; j < n4end; j += 4) {
        int s0 = csr_src[j + 0], s1 = csr_src[j + 1];
        int s2 = csr_src[j + 2], s3 = csr_src[j + 3];
        ushort4 v0 = *reinterpret_cast<const ushort4*>(Hs + (size_t)s0 * 128 + c);
        ushort4 v1 = *reinterpret_cast<const ushort4*>(Hs + (size_t)s1 * 128 + c);
        ushort4 v2 = *reinterpret_cast<const ushort4*>(Hs + (size_t)s2 * 128 + c);
        ushort4 v3 = *reinterpret_cast<const ushort4*>(Hs + (size_t)s3 * 128 + c);
        acc.x += bf2f(v0.x) + bf2f(v1.x) + bf2f(v2.x) + bf2f(v3.x);
        acc.y += bf2f(v0.y) + bf2f(v1.y) + bf2f(v2.y) + bf2f(v3.y);
        acc.z += bf2f(v0.z) + bf2f(v1.z) + bf2f(v2.z) + bf2f(v3.z);
        acc.w += bf2f(v0.w) + bf2f(v1.w) + bf2f(v2.w) + bf2f(v3.w);
    }
    for (; j < end; ++j) {
        int s = csr_src[j];
        ushort4 v = *reinterpret_cast<const ushort4*>(Hs + (size_t)s * 128 + c);
        acc.x += bf2f(v.x); acc.y += bf2f(v.y);
        acc.z += bf2f(v.z); acc.w += bf2f(v.w);
    }
    float di = dinv[n];
    ushort4 sv = *reinterpret_cast<const ushort4*>(Hs + (size_t)n * 128 + c);
    float4 bv = *reinterpret_cast<const float4*>(b1 + c);
    float4 r;
    r.x = fmaxf(fmaf(di, acc.x + bf2f(sv.x), bv.x), 0.f);
    r.y = fmaxf(fmaf(di, acc.y + bf2f(sv.y), bv.y), 0.f);
    r.z = fmaxf(fmaf(di, acc.z + bf2f(sv.z), bv.z), 0.f);
    r.w = fmaxf(fmaf(di, acc.w + bf2f(sv.w), bv.w), 0.f);
    *reinterpret_cast<float4*>(h + (size_t)n * 128 + c) = r;
}

// ---------------- gather layer 2 (40 ch bf16) + fused self-loop/bias ----------------
// one dst node per 10 lanes, lane owns 4 channels (ushort4); edge loop unrolled x4

__global__ __launch_bounds__(256) void gather40(const int* __restrict__ offs,
                                                const int* __restrict__ ends,
                                                const ushort_t* __restrict__ csr_src,
                                                const ushort_t* __restrict__ Hs,
                                                const float* __restrict__ dinv,
                                                const float* __restrict__ b2,
                                                float* __restrict__ out) {
    int idx = blockIdx.x * 256 + threadIdx.x;
    if (idx >= NN * 10) return;
    const int n = idx / 10;
    const int c = (idx - n * 10) * 4;
    const int beg = offs[n], end = ends[n];
    float4 acc = make_float4(0.f, 0.f, 0.f, 0.f);
    int j = beg;
    const int n4end = beg + ((end - beg) & ~3);
    for (; j < n4end; j += 4) {
        int s0 = csr_src[j + 0], s1 = csr_src[j + 1];
        int s2 = csr_src[j + 2], s3 = csr_src[j + 3];
        ushort4 v0 = *reinterpret_cast<const ushort4*>(Hs + (size_t)s0 * 40 + c);
        ushort4 v1 = *reinterpret_cast<const ushort4*>(Hs + (size_t)s1 * 40 + c);
        ushort4 v2 = *reinterpret_cast<const ushort4*>(Hs + (size_t)s2 * 40 + c);
        ushort4 v3 = *reinterpret_cast<const ushort4*>(Hs + (size_t)s3 * 40 + c);
        acc.x += bf2f(v0.x) + bf2f(v1.x) + bf2f(v2.x) + bf2f(v3.x);
        acc.y += bf2f(v0.y) + bf2f(v1.y) + bf2f(v2.y) + bf2f(v3.y);
        acc.z += bf2f(v0.z) + bf2f(v1.z) + bf2f(v2.z) + bf2f(v3.z);
        acc.w += bf2f(v0.w) + bf2f(v1.w) + bf2f(v2.w) + bf2f(v3.w);
    }
    for (; j < end; ++j) {
        int s = csr_src[j];
        ushort4 v = *reinterpret_cast<const ushort4*>(Hs + (size_t)s * 40 + c);
        acc.x += bf2f(v.x); acc.y += bf2f(v.y);
        acc.z += bf2f(v.z); acc.w += bf2f(v.w);
    }
    float di = dinv[n];
    ushort4 sv = *reinterpret_cast<const ushort4*>(Hs + (size_t)n * 40 + c);
    float4 bv = *reinterpret_cast<const float4*>(b2 + c);
    float4 r;
    r.x = fmaf(di, acc.x + bf2f(sv.x), bv.x);
    r.y = fmaf(di, acc.y + bf2f(sv.y), bv.y);
    r.z = fmaf(di, acc.z + bf2f(sv.z), bv.z);
    r.w = fmaf(di, acc.w + bf2f(sv.w), bv.w);
    *reinterpret_cast<float4*>(out + (size_t)n * 40 + c) = r;
}

// ---------------- launch ----------------

extern "C" void kernel_launch(void* const* d_in, const int* in_sizes, int n_in,
                              void* d_out, int out_size, void* d_ws, size_t ws_size,
                              hipStream_t stream) {
    const float* x  = (const float*)d_in[0];
    const int*   ei = (const int*)d_in[1];     // [2, NE]: row0 = src, row1 = dst
    const float* W1 = (const float*)d_in[2];
    const float* b1 = (const float*)d_in[3];
    const float* W2 = (const float*)d_in[4];
    const float* b2 = (const float*)d_in[5];
    float* out = (float*)d_out;

    // workspace layout (4B elements)
    int*      deg_i    = (int*)d_ws;                   // [50048]
    float*    dinv     = (float*)d_ws + 50048;         // [50048]
    int*      offs     = (int*)d_ws + 100096;          // [50048]
    int*      cursor   = (int*)d_ws + 150144;          // [50048] -> ends after fill
    int*      partials = (int*)d_ws + 200192;          // [512]
    ushort_t* csr_src  = (ushort_t*)((int*)d_ws + 200704); // [640000] ushort = 320000 ints
    ushort_t* H1b      = (ushort_t*)((int*)d_ws + 520704);  // NN*128 bf16 = 3.2M ints
    float*    h        = (float*)d_ws + 3720704;       // [6400000]
    ushort_t* H2b      = H1b;                          // alias: H1 dead after gather128

    const int NB = (NN + 255) / 256;                   // 196 scan blocks

    // CSR metadata
    hipMemsetAsync(deg_i, 0, NN * sizeof(int), stream);
    hist_kernel<<<625, 256, 0, stream>>>(ei + NE, deg_i);
    scan_block<<<NB, 256, 0, stream>>>(deg_i, offs, partials, NN);
    scan_partials<<<1, 256, 0, stream>>>(partials, NB);
    finalize_offsets<<<NB, 256, 0, stream>>>(offs, partials, cursor, deg_i, dinv, NN);

    // fused: csr_fill (625 blocks, resident first) | layer-1 GEMM (1564 blocks)
    fused_fill_gemm<<<NFILL + MB1 * 2, 256, 0, stream>>>(ei, cursor, csr_src,
                                                         x, W1, dinv, H1b, NN, 128);

    gather128<<<NN * 32 / 256, 256, 0, stream>>>(offs, cursor, csr_src, H1b, dinv, b1, h);

    // layer 2
    gemm_k128_scaled<<<dim3(MB1, 1), 256, 0, stream>>>(h, W2, dinv, H2b, NN, 40);
    gather40<<<(NN * 10 + 255) / 256, 256, 0, stream>>>(offs, cursor, csr_src, H2b, dinv, b2, out);
}

// Round 13
// 204.312 us; speedup vs baseline: 1.1983x; 1.1275x over previous
//
#include <hip/hip_runtime.h>
#include <cstdint>

#define NN 50000
#define NE 640000
#define ELLW 64                                    // ELL width; deg ~ Poisson(12.8), P(deg>=64) ~ e^-40
#define NFILL 625                                  // ell_fill blocks in fused kernel
#define MB1 782                                    // (NN+63)/64 GEMM row-blocks

typedef unsigned short ushort_t;

__device__ __forceinline__ ushort_t f2bf(float f) {
    unsigned int b = __float_as_uint(f);
    return (ushort_t)((b + 0x7FFF + ((b >> 16) & 1)) >> 16);   // RNE
}
__device__ __forceinline__ float bf2f(ushort_t u) {
    return __uint_as_float(((unsigned int)u) << 16);
}

// ---------------- fused: ell_fill (blocks 0..NFILL-1)  |  GEMM1 (rest) ------
// ELL build: cursor starts at 0; after fill, cursor[n] == degree(n).
// Eliminates hist/scan/finalize entirely (ELL base = n*64, no offsets).
// Fill is TCC/atomic-wall-bound (VALU ~0.25%); GEMM is VALU-bound -> overlap.
// GEMM: fp32, K=128 as two 64-wide steps, 64x64 tile, LDS 33.8 KB -> 4 blocks/CU.
// (Round-5 lesson: register-prefetch A spills; keep LDS tiles.)

__global__ __launch_bounds__(256) void fused_fill_gemm(const int* __restrict__ ei,
                                                       int* __restrict__ cursor,
                                                       ushort_t* __restrict__ ell,
                                                       const float* __restrict__ A,
                                                       const float* __restrict__ B,
                                                       ushort_t* __restrict__ C,
                                                       int M, int N) {
    __shared__ float As[64][68];                  // +4 pad: 2-way bank alias only (free)
    __shared__ __align__(16) float Bs[64][64];

    if (blockIdx.x < NFILL) {
        // ---- ell_fill part: 4 independent edges per thread ----
        int tid = blockIdx.x * 256 + threadIdx.x;  // 160000 threads
#pragma unroll
        for (int k = 0; k < 4; ++k) {
            int e = tid + k * 160000;
            int s = ei[e], d = ei[NE + e];
            int pos = atomicAdd(&cursor[d], 1);
            ell[(size_t)d * ELLW + pos] = (ushort_t)s;
        }
        return;
    }

    // ---- GEMM part (unscaled; dinv not known until fill completes) ----
    const int b  = blockIdx.x - NFILL;
    const int t  = threadIdx.x;
    const int m0 = (b % MB1) * 64;
    const int n0 = (b / MB1) * 64;
    const int tx = t & 15, ty = t >> 4;

    float acc[4][4] = {};

    for (int ks = 0; ks < 2; ++ks) {
#pragma unroll
        for (int i = 0; i < 4; ++i) {
            int idx = i * 256 + t;
            int r = idx >> 4, c4 = idx & 15;
            int gm = m0 + r;
            float4 v = make_float4(0.f, 0.f, 0.f, 0.f);
            if (gm < M) v = *reinterpret_cast<const float4*>(&A[(size_t)gm * 128 + ks * 64 + c4 * 4]);
            As[r][c4 * 4 + 0] = v.x;
            As[r][c4 * 4 + 1] = v.y;
            As[r][c4 * 4 + 2] = v.z;
            As[r][c4 * 4 + 3] = v.w;
        }
#pragma unroll
        for (int i = 0; i < 4; ++i) {
            int idx = i * 256 + t;
            int k = idx >> 4, c4 = idx & 15;
            int gk = ks * 64 + k;
            int gn = n0 + c4 * 4;
            float4 v;
            v.x = (gn + 0 < N) ? B[(size_t)gk * N + gn + 0] : 0.f;
            v.y = (gn + 1 < N) ? B[(size_t)gk * N + gn + 1] : 0.f;
            v.z = (gn + 2 < N) ? B[(size_t)gk * N + gn + 2] : 0.f;
            v.w = (gn + 3 < N) ? B[(size_t)gk * N + gn + 3] : 0.f;
            *reinterpret_cast<float4*>(&Bs[k][c4 * 4]) = v;
        }
        __syncthreads();

#pragma unroll 8
        for (int k = 0; k < 64; ++k) {
            float a0 = As[ty * 4 + 0][k];
            float a1 = As[ty * 4 + 1][k];
            float a2 = As[ty * 4 + 2][k];
            float a3 = As[ty * 4 + 3][k];
            float4 bb = *reinterpret_cast<const float4*>(&Bs[k][tx * 4]);
            acc[0][0] += a0 * bb.x; acc[0][1] += a0 * bb.y; acc[0][2] += a0 * bb.z; acc[0][3] += a0 * bb.w;
            acc[1][0] += a1 * bb.x; acc[1][1] += a1 * bb.y; acc[1][2] += a1 * bb.z; acc[1][3] += a1 * bb.w;
            acc[2][0] += a2 * bb.x; acc[2][1] += a2 * bb.y; acc[2][2] += a2 * bb.z; acc[2][3] += a2 * bb.w;
            acc[3][0] += a3 * bb.x; acc[3][1] += a3 * bb.y; acc[3][2] += a3 * bb.z; acc[3][3] += a3 * bb.w;
        }
        __syncthreads();
    }

#pragma unroll
    for (int i = 0; i < 4; ++i) {
        int gm = m0 + ty * 4 + i;
        if (gm >= M) continue;
        int gn = n0 + tx * 4;
        if (gn + 3 < N) {
            ushort4 o;
            o.x = f2bf(acc[i][0]); o.y = f2bf(acc[i][1]);
            o.z = f2bf(acc[i][2]); o.w = f2bf(acc[i][3]);
            *reinterpret_cast<ushort4*>(&C[(size_t)gm * N + gn]) = o;   // 8B aligned
        } else {
#pragma unroll
            for (int j = 0; j < 4; ++j)
                if (gn + j < N) C[(size_t)gm * N + gn + j] = f2bf(acc[i][j]);
        }
    }
}

// ---------------- scale H1 rows by dinv (deg from cursor) ----------------
// H1b[n][:] *= rsqrt(deg[n]+1); one ushort4 per thread, NN*32 threads exact.

__global__ __launch_bounds__(256) void scale_h1(const int* __restrict__ cursor,
                                                ushort_t* __restrict__ H1b) {
    int idx = blockIdx.x * 256 + threadIdx.x;
    int n = idx >> 5;
    int c = (idx & 31) * 4;
    float di = rsqrtf((float)cursor[n] + 1.0f);
    ushort4 v = *reinterpret_cast<const ushort4*>(H1b + (size_t)n * 128 + c);
    v.x = f2bf(bf2f(v.x) * di);
    v.y = f2bf(bf2f(v.y) * di);
    v.z = f2bf(bf2f(v.z) * di);
    v.w = f2bf(bf2f(v.w) * di);
    *reinterpret_cast<ushort4*>(H1b + (size_t)n * 128 + c) = v;
}

// ---------------- plain scaled GEMM (layer 2, N=40): row scale = rsqrt(deg+1) ----

__global__ __launch_bounds__(256) void gemm_k128_scaled(const float* __restrict__ A,
                                                        const float* __restrict__ B,
                                                        const int* __restrict__ cursor,
                                                        ushort_t* __restrict__ C,
                                                        int M, int N) {
    __shared__ float As[64][68];
    __shared__ __align__(16) float Bs[64][64];
    const int t  = threadIdx.x;
    const int m0 = blockIdx.x * 64;
    const int n0 = blockIdx.y * 64;
    const int tx = t & 15, ty = t >> 4;

    float acc[4][4] = {};

    for (int ks = 0; ks < 2; ++ks) {
#pragma unroll
        for (int i = 0; i < 4; ++i) {
            int idx = i * 256 + t;
            int r = idx >> 4, c4 = idx & 15;
            int gm = m0 + r;
            float4 v = make_float4(0.f, 0.f, 0.f, 0.f);
            if (gm < M) v = *reinterpret_cast<const float4*>(&A[(size_t)gm * 128 + ks * 64 + c4 * 4]);
            As[r][c4 * 4 + 0] = v.x;
            As[r][c4 * 4 + 1] = v.y;
            As[r][c4 * 4 + 2] = v.z;
            As[r][c4 * 4 + 3] = v.w;
        }
#pragma unroll
        for (int i = 0; i < 4; ++i) {
            int idx = i * 256 + t;
            int k = idx >> 4, c4 = idx & 15;
            int gk = ks * 64 + k;
            int gn = n0 + c4 * 4;
            float4 v;
            v.x = (gn + 0 < N) ? B[(size_t)gk * N + gn + 0] : 0.f;
            v.y = (gn + 1 < N) ? B[(size_t)gk * N + gn + 1] : 0.f;
            v.z = (gn + 2 < N) ? B[(size_t)gk * N + gn + 2] : 0.f;
            v.w = (gn + 3 < N) ? B[(size_t)gk * N + gn + 3] : 0.f;
            *reinterpret_cast<float4*>(&Bs[k][c4 * 4]) = v;
        }
        __syncthreads();

#pragma unroll 8
        for (int k = 0; k < 64; ++k) {
            float a0 = As[ty * 4 + 0][k];
            float a1 = As[ty * 4 + 1][k];
            float a2 = As[ty * 4 + 2][k];
            float a3 = As[ty * 4 + 3][k];
            float4 bb = *reinterpret_cast<const float4*>(&Bs[k][tx * 4]);
            acc[0][0] += a0 * bb.x; acc[0][1] += a0 * bb.y; acc[0][2] += a0 * bb.z; acc[0][3] += a0 * bb.w;
            acc[1][0] += a1 * bb.x; acc[1][1] += a1 * bb.y; acc[1][2] += a1 * bb.z; acc[1][3] += a1 * bb.w;
            acc[2][0] += a2 * bb.x; acc[2][1] += a2 * bb.y; acc[2][2] += a2 * bb.z; acc[2][3] += a2 * bb.w;
            acc[3][0] += a3 * bb.x; acc[3][1] += a3 * bb.y; acc[3][2] += a3 * bb.z; acc[3][3] += a3 * bb.w;
        }
        __syncthreads();
    }

#pragma unroll
    for (int i = 0; i < 4; ++i) {
        int gm = m0 + ty * 4 + i;
        if (gm >= M) continue;
        float s = rsqrtf((float)cursor[gm] + 1.0f);
        int gn = n0 + tx * 4;
        if (gn + 3 < N) {
            ushort4 o;
            o.x = f2bf(acc[i][0] * s); o.y = f2bf(acc[i][1] * s);
            o.z = f2bf(acc[i][2] * s); o.w = f2bf(acc[i][3] * s);
            *reinterpret_cast<ushort4*>(&C[(size_t)gm * N + gn]) = o;
        } else {
#pragma unroll
            for (int j = 0; j < 4; ++j)
                if (gn + j < N) C[(size_t)gm * N + gn + j] = f2bf(acc[i][j] * s);
        }
    }
}

// ---------------- gather layer 1 (128 ch bf16) + fused self-loop/bias/ReLU ----------------
// Hs = dinv[m]*H[m] (pre-scaled); result = relu(dinv[n]*(sum + Hs[n]) + b)
// one dst node per 32 lanes, lane owns 4 channels (ushort4 = 8B); edge loop unrolled x4

__global__ __launch_bounds__(256) void gather128(const int* __restrict__ cursor,
                                                 const ushort_t* __restrict__ ell,
                                                 const ushort_t* __restrict__ Hs,
                                                 const float* __restrict__ b1,
                                                 float* __restrict__ h) {
    const int c = (threadIdx.x & 31) * 4;
    const int n = (blockIdx.x * 256 + threadIdx.x) >> 5;    // grid exact: NN*32 threads
    const int deg = cursor[n];
    const ushort_t* en = ell + (size_t)n * ELLW;
    float4 acc = make_float4(0.f, 0.f, 0.f, 0.f);
    int j = 0;
    const int n4end = deg & ~3;
    for (; j < n4end; j += 4) {
        int s0 = en[j + 0], s1 = en[j + 1];
        int s2 = en[j + 2], s3 = en[j + 3];
        ushort4 v0 = *reinterpret_cast<const ushort4*>(Hs + (size_t)s0 * 128 + c);
        ushort4 v1 = *reinterpret_cast<const ushort4*>(Hs + (size_t)s1 * 128 + c);
        ushort4 v2 = *reinterpret_cast<const ushort4*>(Hs + (size_t)s2 * 128 + c);
        ushort4 v3 = *reinterpret_cast<const ushort4*>(Hs + (size_t)s3 * 128 + c);
        acc.x += bf2f(v0.x) + bf2f(v1.x) + bf2f(v2.x) + bf2f(v3.x);
        acc.y += bf2f(v0.y) + bf2f(v1.y) + bf2f(v2.y) + bf2f(v3.y);
        acc.z += bf2f(v0.z) + bf2f(v1.z) + bf2f(v2.z) + bf2f(v3.z);
        acc.w += bf2f(v0.w) + bf2f(v1.w) + bf2f(v2.w) + bf2f(v3.w);
    }
    for (; j < deg; ++j) {
        int s = en[j];
        ushort4 v = *reinterpret_cast<const ushort4*>(Hs + (size_t)s * 128 + c);
        acc.x += bf2f(v.x); acc.y += bf2f(v.y);
        acc.z += bf2f(v.z); acc.w += bf2f(v.w);
    }
    float di = rsqrtf((float)deg + 1.0f);
    ushort4 sv = *reinterpret_cast<const ushort4*>(Hs + (size_t)n * 128 + c);
    float4 bv = *reinterpret_cast<const float4*>(b1 + c);
    float4 r;
    r.x = fmaxf(fmaf(di, acc.x + bf2f(sv.x), bv.x), 0.f);
    r.y = fmaxf(fmaf(di, acc.y + bf2f(sv.y), bv.y), 0.f);
    r.z = fmaxf(fmaf(di, acc.z + bf2f(sv.z), bv.z), 0.f);
    r.w = fmaxf(fmaf(di, acc.w + bf2f(sv.w), bv.w), 0.f);
    *reinterpret_cast<float4*>(h + (size_t)n * 128 + c) = r;
}

// ---------------- gather layer 2 (40 ch bf16) + fused self-loop/bias ----------------
// one dst node per 10 lanes, lane owns 4 channels (ushort4); edge loop unrolled x4

__global__ __launch_bounds__(256) void gather40(const int* __restrict__ cursor,
                                                const ushort_t* __restrict__ ell,
                                                const ushort_t* __restrict__ Hs,
                                                const float* __restrict__ b2,
                                                float* __restrict__ out) {
    int idx = blockIdx.x * 256 + threadIdx.x;
    if (idx >= NN * 10) return;
    const int n = idx / 10;
    const int c = (idx - n * 10) * 4;
    const int deg = cursor[n];
    const ushort_t* en = ell + (size_t)n * ELLW;
    float4 acc = make_float4(0.f, 0.f, 0.f, 0.f);
    int j = 0;
    const int n4end = deg & ~3;
    for (; j < n4end; j += 4) {
        int s0 = en[j + 0], s1 = en[j + 1];
        int s2 = en[j + 2], s3 = en[j + 3];
        ushort4 v0 = *reinterpret_cast<const ushort4*>(Hs + (size_t)s0 * 40 + c);
        ushort4 v1 = *reinterpret_cast<const ushort4*>(Hs + (size_t)s1 * 40 + c);
        ushort4 v2 = *reinterpret_cast<const ushort4*>(Hs + (size_t)s2 * 40 + c);
        ushort4 v3 = *reinterpret_cast<const ushort4*>(Hs + (size_t)s3 * 40 + c);
        acc.x += bf2f(v0.x) + bf2f(v1.x) + bf2f(v2.x) + bf2f(v3.x);
        acc.y += bf2f(v0.y) + bf2f(v1.y) + bf2f(v2.y) + bf2f(v3.y);
        acc.z += bf2f(v0.z) + bf2f(v1.z) + bf2f(v2.z) + bf2f(v3.z);
        acc.w += bf2f(v0.w) + bf2f(v1.w) + bf2f(v2.w) + bf2f(v3.w);
    }
    for (; j < deg; ++j) {
        int s = en[j];
        ushort4 v = *reinterpret_cast<const ushort4*>(Hs + (size_t)s * 40 + c);
        acc.x += bf2f(v.x); acc.y += bf2f(v.y);
        acc.z += bf2f(v.z); acc.w += bf2f(v.w);
    }
    float di = rsqrtf((float)deg + 1.0f);
    ushort4 sv = *reinterpret_cast<const ushort4*>(Hs + (size_t)n * 40 + c);
    float4 bv = *reinterpret_cast<const float4*>(b2 + c);
    float4 r;
    r.x = fmaf(di, acc.x + bf2f(sv.x), bv.x);
    r.y = fmaf(di, acc.y + bf2f(sv.y), bv.y);
    r.z = fmaf(di, acc.z + bf2f(sv.z), bv.z);
    r.w = fmaf(di, acc.w + bf2f(sv.w), bv.w);
    *reinterpret_cast<float4*>(out + (size_t)n * 40 + c) = r;
}

// ---------------- launch ----------------

extern "C" void kernel_launch(void* const* d_in, const int* in_sizes, int n_in,
                              void* d_out, int out_size, void* d_ws, size_t ws_size,
                              hipStream_t stream) {
    const float* x  = (const float*)d_in[0];
    const int*   ei = (const int*)d_in[1];     // [2, NE]: row0 = src, row1 = dst
    const float* W1 = (const float*)d_in[2];
    const float* b1 = (const float*)d_in[3];
    const float* W2 = (const float*)d_in[4];
    const float* b2 = (const float*)d_in[5];
    float* out = (float*)d_out;

    // workspace layout (4B elements)
    int*      cursor = (int*)d_ws;                          // [50048] -> deg after fill
    ushort_t* ell    = (ushort_t*)((int*)d_ws + 50048);     // [NN*64] ushort = 1.6M ints
    ushort_t* H1b    = (ushort_t*)((int*)d_ws + 1650048);   // [NN*128] bf16 = 3.2M ints
    float*    h      = (float*)d_ws + 4850048;              // [6400000]
    ushort_t* H2b    = H1b;                                 // alias: H1 dead after gather128

    hipMemsetAsync(cursor, 0, NN * sizeof(int), stream);

    // fused: ell_fill (625 blocks, resident first) | layer-1 GEMM (1564 blocks)
    fused_fill_gemm<<<NFILL + MB1 * 2, 256, 0, stream>>>(ei, cursor, ell,
                                                         x, W1, H1b, NN, 128);

    // H1b *= rsqrt(deg+1) row-wise (deg now final in cursor)
    scale_h1<<<NN * 32 / 256, 256, 0, stream>>>(cursor, H1b);

    gather128<<<NN * 32 / 256, 256, 0, stream>>>(cursor, ell, H1b, b1, h);

    // layer 2
    gemm_k128_scaled<<<dim3(MB1, 1), 256, 0, stream>>>(h, W2, cursor, H2b, NN, 40);
    gather40<<<(NN * 10 + 255) / 256, 256, 0, stream>>>(cursor, ell, H2b, b2, out);
}